// Round 6
// baseline (205.761 us; speedup 1.0000x reference)
//
#include <hip/hip_runtime.h>
#include <hip/hip_bf16.h>
#include <math.h>

#define N_NODES 3072
#define NPAD    3104    // V^T column stride: N + 32 zeroed pad cols (aligned PV loads)
#define DIM     256
#define NH      8
#define HD      32
#define E_EDGES 98304
#define B_GRAPHS 16
#define TBUCKETS 192    // global 16-row tile buckets (N/16)
#define BCAP    1024    // bucket capacity (mean 512, sigma ~23 -> 22-sigma margin)
#define MAXC    326     // fp32 score stride (326%32==6 -> 2-way max on C-writes, free)
#define PADP    328     // bf16 P stride (656B rows, 16B-aligned frag reads)
#define TR      16      // rows per attention tile
#define SCALE   0.17677669529663689f   // 1/sqrt(32)

typedef __attribute__((ext_vector_type(8))) short bf16x8;
typedef __attribute__((ext_vector_type(4))) float f32x4;
typedef __attribute__((ext_vector_type(4))) unsigned short ushort4v;

__device__ inline unsigned short f2b(float f) {
    __hip_bfloat16 h = __float2bfloat16(f);
    return *reinterpret_cast<unsigned short*>(&h);
}
__device__ inline float b2f(unsigned short u) {
    __hip_bfloat16 h = *reinterpret_cast<__hip_bfloat16*>(&u);
    return __bfloat162float(h);
}

// ---------------- K1 prep: x split | W^T split | VT-pad/gstart | edge bucket+bias ----
// grid 1440: [0,768) x-split, [768,1024) W-transpose, [1024,1056) misc, [1056,1440) edges
// tcur (192 ints) zeroed by hipMemsetAsync BEFORE this kernel.
__global__ __launch_bounds__(256) void prep(
    const float* __restrict__ x,
    const float* __restrict__ Wq, const float* __restrict__ Wk,
    const float* __restrict__ Wv, const float* __restrict__ Wo,
    const float* __restrict__ ea, const float* __restrict__ We,
    const float* __restrict__ be,
    const int* __restrict__ erow, const int* __restrict__ ecolin,
    unsigned short* __restrict__ xh, unsigned short* __restrict__ xl,
    unsigned short* __restrict__ Wth, unsigned short* __restrict__ Wtl,
    unsigned short* __restrict__ VT, float* __restrict__ ebias,
    const int* __restrict__ batch, int* __restrict__ gstart,
    int* __restrict__ tcur, unsigned long long* __restrict__ tbuck)
{
    const int b = blockIdx.x, t = threadIdx.x;
    if (b < 768) {                       // ---- x hi/lo split, float4 granularity
        const int gid = b * 256 + t;
        float4 v = ((const float4*)x)[gid];
        ushort4v h, l;
        float c[4] = {v.x, v.y, v.z, v.w};
        #pragma unroll
        for (int i = 0; i < 4; ++i) {
            unsigned short hi = f2b(c[i]);
            h[i] = hi;
            l[i] = f2b(c[i] - b2f(hi));
        }
        ((ushort4v*)xh)[gid] = h;
        ((ushort4v*)xl)[gid] = l;
    } else if (b < 1024) {               // ---- W transpose 32x32 tiles, hi/lo
        __shared__ float tile[32][33];
        const int wb = b - 768;
        const int mat = wb >> 6, tidx = wb & 63;
        const int tk = (tidx >> 3) * 32, tn = (tidx & 7) * 32;
        const float* W = (mat == 0) ? Wq : (mat == 1) ? Wk : (mat == 2) ? Wv : Wo;
        const int kk = t >> 5, nn = t & 31;
        #pragma unroll
        for (int p = 0; p < 4; ++p)
            tile[nn][kk + p * 8] = W[(size_t)(tk + kk + p * 8) * DIM + tn + nn];
        __syncthreads();
        const int n = t >> 3, kq = (t & 7) * 4;
        ushort4v h, l;
        #pragma unroll
        for (int i = 0; i < 4; ++i) {
            float v = tile[n][kq + i];
            unsigned short hi = f2b(v);
            h[i] = hi;
            l[i] = f2b(v - b2f(hi));
        }
        size_t o = (size_t)mat * DIM * DIM + (size_t)(tn + n) * DIM + tk + kq;
        *(ushort4v*)(Wth + o) = h;
        *(ushort4v*)(Wtl + o) = l;
    } else if (b < 1056) {               // ---- VT pad zero + graph ranges
        const int i = (b - 1024) * 256 + t;          // [0, 8192)
        VT[(size_t)(i >> 5) * NPAD + N_NODES + (i & 31)] = 0;
        if (i < N_NODES) {
            int bb = batch[i];
            int bp = (i == 0) ? -1 : batch[i - 1];
            for (int g = bp + 1; g <= bb; ++g) gstart[g] = i;
            if (i == N_NODES - 1)
                for (int g = bb + 1; g <= B_GRAPHS; ++g) gstart[g] = N_NODES;
        }
    } else {                             // ---- edge bucket (by row>>4) + per-edge bias
        const int e = (b - 1056) * 256 + t;
        const int row = erow[e];
        const int col = ecolin[e];
        const int tr = row >> 4;
        int pos = atomicAdd(&tcur[tr], 1);
        if (pos < BCAP)
            tbuck[(size_t)tr * BCAP + pos] =
                ((unsigned long long)e << 24) |
                ((unsigned long long)(row & 15) << 12) |
                (unsigned long long)col;
        float4 a = ((const float4*)ea)[e];
        #pragma unroll
        for (int h = 0; h < NH; ++h) {
            float bb = fmaf(a.x, We[0 * NH + h],
                       fmaf(a.y, We[1 * NH + h],
                       fmaf(a.z, We[2 * NH + h],
                       fmaf(a.w, We[3 * NH + h], be[h]))));
            ebias[(size_t)h * E_EDGES + e] = bb;
        }
    }
}

// ---------------- K2: QKV split-bf16 MFMA ----------------
// grid 576, block 256 = 4 waves; wave tile 16x64. u: bx=u%96 (32-row block),
// by=u/96 in [0,6): mat=by>>1. mat<2 -> Q/K row-major; mat==2 -> V^T.
__global__ __launch_bounds__(256) void qkv_mfma(
    const unsigned short* __restrict__ xh, const unsigned short* __restrict__ xl,
    const unsigned short* __restrict__ Wth, const unsigned short* __restrict__ Wtl,
    const float* __restrict__ bq, const float* __restrict__ bk, const float* __restrict__ bv,
    unsigned short* __restrict__ Qb, unsigned short* __restrict__ Kb,
    unsigned short* __restrict__ VT)
{
    const int u = blockIdx.x;
    const int t = threadIdx.x;
    const int w = t >> 6, lane = t & 63;
    const int l16 = lane & 15, lq = lane >> 4;
    const int bx = u % 96, by = u / 96;
    const int mat = by >> 1;
    const int rb = bx * 32 + (w & 1) * 16;
    const int nb = (by & 1) * 128 + (w >> 1) * 64;
    const unsigned short* Wh = Wth + (size_t)mat * DIM * DIM;
    const unsigned short* Wl = Wtl + (size_t)mat * DIM * DIM;

    f32x4 acc[4] = {{0,0,0,0},{0,0,0,0},{0,0,0,0},{0,0,0,0}};

    if (mat < 2) {                       // ---- Q/K: A = x rows, B = W^T rows
        const size_t arow = (size_t)(rb + l16) * DIM + (lq << 3);
        #pragma unroll
        for (int kc = 0; kc < 8; ++kc) {
            const int k = kc * 32;
            bf16x8 ah = *(const bf16x8*)(xh + arow + k);
            bf16x8 al = *(const bf16x8*)(xl + arow + k);
            #pragma unroll
            for (int ct = 0; ct < 4; ++ct) {
                const size_t bo_ = (size_t)(nb + ct * 16 + l16) * DIM + k + (lq << 3);
                bf16x8 bh = *(const bf16x8*)(Wh + bo_);
                bf16x8 bl = *(const bf16x8*)(Wl + bo_);
                acc[ct] = __builtin_amdgcn_mfma_f32_16x16x32_bf16(ah, bh, acc[ct], 0, 0, 0);
                acc[ct] = __builtin_amdgcn_mfma_f32_16x16x32_bf16(ah, bl, acc[ct], 0, 0, 0);
                acc[ct] = __builtin_amdgcn_mfma_f32_16x16x32_bf16(al, bh, acc[ct], 0, 0, 0);
            }
        }
        const float* bias = (mat == 0) ? bq : bk;
        unsigned short* outp = (mat == 0) ? Qb : Kb;
        #pragma unroll
        for (int ct = 0; ct < 4; ++ct) {
            const int n = nb + ct * 16 + l16;
            const float bvl = bias[n];
            #pragma unroll
            for (int r = 0; r < 4; ++r)
                outp[(size_t)(rb + lq * 4 + r) * DIM + n] = f2b(acc[ct][r] + bvl);
        }
    } else {                             // ---- V^T: A = Wv^T rows, B = x rows
        const size_t brow = (size_t)(rb + l16) * DIM + (lq << 3);
        #pragma unroll
        for (int kc = 0; kc < 8; ++kc) {
            const int k = kc * 32;
            bf16x8 bxh = *(const bf16x8*)(xh + brow + k);
            bf16x8 bxl = *(const bf16x8*)(xl + brow + k);
            #pragma unroll
            for (int ct = 0; ct < 4; ++ct) {
                const size_t ao_ = (size_t)(nb + ct * 16 + l16) * DIM + k + (lq << 3);
                bf16x8 awh = *(const bf16x8*)(Wh + ao_);
                bf16x8 awl = *(const bf16x8*)(Wl + ao_);
                acc[ct] = __builtin_amdgcn_mfma_f32_16x16x32_bf16(awh, bxh, acc[ct], 0, 0, 0);
                acc[ct] = __builtin_amdgcn_mfma_f32_16x16x32_bf16(awh, bxl, acc[ct], 0, 0, 0);
                acc[ct] = __builtin_amdgcn_mfma_f32_16x16x32_bf16(awl, bxh, acc[ct], 0, 0, 0);
            }
        }
        #pragma unroll
        for (int ct = 0; ct < 4; ++ct) {
            #pragma unroll
            for (int r = 0; r < 4; ++r) {
                const int ncol = nb + ct * 16 + lq * 4 + r;   // output channel (h*HD+kout)
                VT[(size_t)ncol * NPAD + rb + l16] = f2b(acc[ct][r] + bv[ncol]);
            }
        }
    }
}

// ---------------- K3: MFMA block-diagonal attention ----------------
// grid (16 graphs, 24 tiles, 8 heads), block 256 (4 waves), TR=16 rows/tile.
// 16-aligned column base ags = gs & ~15; dead prefix cols masked P=0.
// Bias phase scans <=2 global row-tile buckets with a range filter (no CSR).
__global__ __launch_bounds__(256) void attn(
    const unsigned short* __restrict__ Qb, const unsigned short* __restrict__ Kb,
    const unsigned short* __restrict__ VT,
    const int* __restrict__ gstart,
    const int* __restrict__ tcur, const unsigned long long* __restrict__ tbuck,
    const float* __restrict__ ebias,
    unsigned short* __restrict__ preh, unsigned short* __restrict__ prel)
{
    __shared__ float s[TR][MAXC];                 // scores fp32; reused as PV reduce buf
    __shared__ unsigned short pb[TR][PADP];       // probabilities bf16 (A-frag layout)
    __shared__ float rowinv[TR];

    const int g = blockIdx.x, tile = blockIdx.y, h = blockIdx.z;
    const int gs = gstart[g], ge = gstart[g + 1];
    const int row0 = gs + tile * TR;
    if (row0 >= ge) return;
    const int nrows = min(TR, ge - row0);
    const int ncols = ge - gs;
    const int ags   = gs & ~15;                   // aligned column base
    const int coff  = gs - ags;                   // 0..15 dead prefix cols
    const int tcols = coff + ncols;
    const int cpad  = (tcols + 31) & ~31;
    const int t = threadIdx.x;
    const int wave = t >> 6, lane = t & 63;
    const int l16 = lane & 15, lq = lane >> 4;

    // ---- QK^T via MFMA: A = Q rows, B = K rows (head-dim contraction)
    {
        int arow = min(row0 + l16, N_NODES - 1);
        const bf16x8 aq = *(const bf16x8*)(Qb + (size_t)arow * DIM + h * HD + (lq << 3));
        const int nchunk16 = (tcols + 15) >> 4;
        for (int j = wave; j < nchunk16; j += 4) {
            const int c0 = j << 4;
            int krow = min(ags + c0 + l16, N_NODES - 1);
            bf16x8 bk = *(const bf16x8*)(Kb + (size_t)krow * DIM + h * HD + (lq << 3));
            f32x4 d = {0.f, 0.f, 0.f, 0.f};
            d = __builtin_amdgcn_mfma_f32_16x16x32_bf16(aq, bk, d, 0, 0, 0);
            const int col = c0 + l16, rbase = lq * 4;
            #pragma unroll
            for (int r = 0; r < 4; ++r) s[rbase + r][col] = d[r] * SCALE;
        }
    }
    __syncthreads();

    // ---- edge-bias scatter from <=2 row-tile buckets (duplicates via LDS atomics)
    {
        const int tr0 = row0 >> 4;
        const int trN = (row0 + nrows - 1) >> 4;
        for (int tb = tr0; tb <= trN; ++tb) {
            const int cnt = min(tcur[tb], BCAP);
            const unsigned long long* bk = tbuck + (size_t)tb * BCAP;
            const int rb0 = tb << 4;
            for (int idx = t; idx < cnt; idx += 256) {
                unsigned long long p = bk[idx];
                int col = (int)(p & 0xFFFu);
                int r   = rb0 + (int)((p >> 12) & 15u) - row0;
                int c   = col - gs;
                if (r >= 0 && r < nrows && c >= 0 && c < ncols)
                    atomicAdd(&s[r][coff + c],
                              ebias[(size_t)h * E_EDGES + (size_t)(p >> 24)]);
            }
        }
    }
    __syncthreads();

    // ---- softmax: 16 lanes/row; emit bf16 P, zero outside [coff, tcols)
    {
        const int r = t >> 4, sub = t & 15;
        if (r < nrows) {
            float m = -INFINITY;
            for (int c = coff + sub; c < tcols; c += 16) m = fmaxf(m, s[r][c]);
            m = fmaxf(m, __shfl_xor(m, 1, 16));
            m = fmaxf(m, __shfl_xor(m, 2, 16));
            m = fmaxf(m, __shfl_xor(m, 4, 16));
            m = fmaxf(m, __shfl_xor(m, 8, 16));
            float sum = 0.f;
            for (int c = sub; c < cpad; c += 16) {
                if (c >= coff && c < tcols) {
                    float e = __expf(s[r][c] - m);
                    sum += e;
                    pb[r][c] = f2b(e);
                } else {
                    pb[r][c] = 0;
                }
            }
            sum += __shfl_xor(sum, 1, 16);
            sum += __shfl_xor(sum, 2, 16);
            sum += __shfl_xor(sum, 4, 16);
            sum += __shfl_xor(sum, 8, 16);
            if (sub == 0) rowinv[r] = 1.0f / sum;
        } else {
            for (int c = sub; c < cpad; c += 16) pb[r][c] = 0;
        }
    }
    __syncthreads();

    // ---- PV via MFMA: B-frag = one aligned 16B V^T load per chunk
    f32x4 o = {0.f, 0.f, 0.f, 0.f};
    {
        const int half = wave >> 1, par = wave & 1;
        const int kout = l16 + (half << 4);
        const int nchunk32 = cpad >> 5;
        const unsigned short* vrow = VT + (size_t)(h * HD + kout) * NPAD + ags + (lq << 3);
        for (int j = par; j < nchunk32; j += 2) {
            const int c0 = j << 5;
            bf16x8 ap = *(const bf16x8*)(&pb[l16][c0 + (lq << 3)]);
            bf16x8 bv = *(const bf16x8*)(vrow + c0);
            o = __builtin_amdgcn_mfma_f32_16x16x32_bf16(ap, bv, o, 0, 0, 0);
        }
    }
    __syncthreads();
    {
        float* red = &s[0][0];       // [4 waves][16 rows][16 kout], stride 17
        const int rbase = lq * 4;
        #pragma unroll
        for (int r = 0; r < 4; ++r)
            red[((wave << 4) + rbase + r) * 17 + l16] = o[r];
    }
    __syncthreads();
    {
        const int row = t >> 4, kl = t & 15;
        if (row < nrows) {
            float* red = &s[0][0];
            float v0 = red[(row) * 17 + kl]        + red[(16 + row) * 17 + kl];
            float v1 = red[(32 + row) * 17 + kl]   + red[(48 + row) * 17 + kl];
            float sc = rowinv[row];
            size_t ob = (size_t)(row0 + row) * DIM + h * HD;
            float f0 = v0 * sc, f1 = v1 * sc;
            unsigned short h0 = f2b(f0), h1 = f2b(f1);
            preh[ob + kl]      = h0;
            preh[ob + 16 + kl] = h1;
            prel[ob + kl]      = f2b(f0 - b2f(h0));
            prel[ob + 16 + kl] = f2b(f1 - b2f(h1));
        }
    }
}

// ---------------- K4: output projection via split-bf16 MFMA ----------------
__global__ __launch_bounds__(256) void out_mfma(
    const unsigned short* __restrict__ preh, const unsigned short* __restrict__ prel,
    const unsigned short* __restrict__ Wth, const unsigned short* __restrict__ Wtl,
    const float* __restrict__ bo, float* __restrict__ out)
{
    const int t = threadIdx.x, w = t >> 6, lane = t & 63;
    const int l16 = lane & 15, lq = lane >> 4;
    const int rb = blockIdx.x * 16;
    const int nb = blockIdx.y * 128 + w * 32;
    const unsigned short* Wh = Wth + (size_t)3 * DIM * DIM;   // Wo^T
    const unsigned short* Wl = Wtl + (size_t)3 * DIM * DIM;

    f32x4 acc[2] = {{0,0,0,0},{0,0,0,0}};
    const size_t arow = (size_t)(rb + l16) * DIM + (lq << 3);

    #pragma unroll
    for (int kc = 0; kc < 8; ++kc) {
        const int k = kc * 32;
        bf16x8 ah = *(const bf16x8*)(preh + arow + k);
        bf16x8 al = *(const bf16x8*)(prel + arow + k);
        #pragma unroll
        for (int ct = 0; ct < 2; ++ct) {
            const size_t bo_ = (size_t)(nb + ct * 16 + l16) * DIM + k + (lq << 3);
            bf16x8 bh = *(const bf16x8*)(Wh + bo_);
            bf16x8 bl = *(const bf16x8*)(Wl + bo_);
            acc[ct] = __builtin_amdgcn_mfma_f32_16x16x32_bf16(ah, bh, acc[ct], 0, 0, 0);
            acc[ct] = __builtin_amdgcn_mfma_f32_16x16x32_bf16(ah, bl, acc[ct], 0, 0, 0);
            acc[ct] = __builtin_amdgcn_mfma_f32_16x16x32_bf16(al, bh, acc[ct], 0, 0, 0);
        }
    }

    #pragma unroll
    for (int ct = 0; ct < 2; ++ct) {
        const int n = nb + ct * 16 + l16;
        const float bvl = bo[n];
        #pragma unroll
        for (int r = 0; r < 4; ++r)
            out[(size_t)(rb + lq * 4 + r) * DIM + n] = acc[ct][r] + bvl;
    }
}

// ---------------- launch ----------------
extern "C" void kernel_launch(void* const* d_in, const int* in_sizes, int n_in,
                              void* d_out, int out_size, void* d_ws, size_t ws_size,
                              hipStream_t stream) {
    const float* x   = (const float*)d_in[0];
    const float* ea  = (const float*)d_in[1];
    const float* Wq  = (const float*)d_in[2];  const float* bq = (const float*)d_in[3];
    const float* Wk  = (const float*)d_in[4];  const float* bk = (const float*)d_in[5];
    const float* Wv  = (const float*)d_in[6];  const float* bv = (const float*)d_in[7];
    const float* Wo  = (const float*)d_in[8];  const float* bo = (const float*)d_in[9];
    const float* We  = (const float*)d_in[10]; const float* be = (const float*)d_in[11];
    const int*   eidx  = (const int*)d_in[12];
    const int*   batch = (const int*)d_in[13];
    const int* erow   = eidx;
    const int* ecolin = eidx + E_EDGES;

    const size_t ND = (size_t)N_NODES * DIM;     // 786432
    const size_t WD = (size_t)DIM * DIM;         // 65536

    unsigned short* Qb   = (unsigned short*)d_ws;
    unsigned short* Kb   = Qb + ND;
    unsigned short* VT   = Kb + ND;              // [256][NPAD]
    unsigned short* preh = VT + (size_t)DIM * NPAD;
    unsigned short* prel = preh + ND;
    unsigned short* xh   = prel + ND;
    unsigned short* xl   = xh + ND;
    unsigned short* Wth  = xl + ND;              // 4 * WD
    unsigned short* Wtl  = Wth + 4 * WD;
    unsigned long long* tbuck = (unsigned long long*)(Wtl + 4 * WD);  // 192*1024 u64 (8B-aligned)
    float* ebias  = (float*)(tbuck + (size_t)TBUCKETS * BCAP);        // [NH][E]
    int* tcur     = (int*)(ebias + (size_t)NH * E_EDGES);             // 192
    int* gstart   = tcur + TBUCKETS;                                  // B+1

    hipMemsetAsync(tcur, 0, TBUCKETS * sizeof(int), stream);
    prep<<<dim3(1440), dim3(256), 0, stream>>>(x, Wq, Wk, Wv, Wo, ea, We, be,
                                               erow, ecolin, xh, xl, Wth, Wtl,
                                               VT, ebias, batch, gstart, tcur, tbuck);
    qkv_mfma<<<dim3(576), dim3(256), 0, stream>>>(xh, xl, Wth, Wtl, bq, bk, bv,
                                                  Qb, Kb, VT);
    attn<<<dim3(B_GRAPHS, 24, NH), dim3(256), 0, stream>>>(Qb, Kb, VT, gstart,
                                                           tcur, tbuck, ebias, preh, prel);
    out_mfma<<<dim3(192, 2), dim3(256), 0, stream>>>(preh, prel, Wth, Wtl, bo, (float*)d_out);
}

// Round 7
// 157.725 us; speedup vs baseline: 1.3046x; 1.3046x over previous
//
#include <hip/hip_runtime.h>
#include <hip/hip_bf16.h>
#include <math.h>

#define N_NODES 3072
#define NPAD    3104    // V^T column stride: N + 32 zeroed pad cols (aligned PV loads)
#define DIM     256
#define NH      8
#define HD      32
#define E_EDGES 98304
#define B_GRAPHS 16
#define RCAP    96      // per-row bucket capacity (mean 32, 11-sigma margin; fixed seed)
#define MAXC    326     // fp32 score stride (326%32==6 -> 2-way max on C-writes, free)
#define PADP    328     // bf16 P stride (656B rows, 16B-aligned frag reads)
#define TR      16      // rows per attention tile
#define SCALE   0.17677669529663689f   // 1/sqrt(32)

typedef __attribute__((ext_vector_type(8))) short bf16x8;
typedef __attribute__((ext_vector_type(4))) float f32x4;
typedef __attribute__((ext_vector_type(4))) unsigned short ushort4v;

__device__ inline unsigned short f2b(float f) {
    __hip_bfloat16 h = __float2bfloat16(f);
    return *reinterpret_cast<unsigned short*>(&h);
}
__device__ inline float b2f(unsigned short u) {
    __hip_bfloat16 h = *reinterpret_cast<__hip_bfloat16*>(&u);
    return __bfloat162float(h);
}

// ---------------- K1 prep: x split | W^T split | VT-pad/gstart | edge bucket+bias ----
// grid 1440: [0,768) x-split, [768,1024) W-transpose, [1024,1056) misc, [1056,1440) edges
// tcur (3072 ints) zeroed by hipMemsetAsync BEFORE this kernel.
// Per-ROW buckets: ~32 atomics/address (R6's 192 tile-buckets had 512/address ->
// 61us same-address atomic serialization; this restores R5's contention level).
__global__ __launch_bounds__(256) void prep(
    const float* __restrict__ x,
    const float* __restrict__ Wq, const float* __restrict__ Wk,
    const float* __restrict__ Wv, const float* __restrict__ Wo,
    const float* __restrict__ ea, const float* __restrict__ We,
    const float* __restrict__ be,
    const int* __restrict__ erow, const int* __restrict__ ecolin,
    unsigned short* __restrict__ xh, unsigned short* __restrict__ xl,
    unsigned short* __restrict__ Wth, unsigned short* __restrict__ Wtl,
    unsigned short* __restrict__ VT, float* __restrict__ ebias,
    const int* __restrict__ batch, int* __restrict__ gstart,
    int* __restrict__ tcur, unsigned int* __restrict__ tbuck)
{
    const int b = blockIdx.x, t = threadIdx.x;
    if (b < 768) {                       // ---- x hi/lo split, float4 granularity
        const int gid = b * 256 + t;
        float4 v = ((const float4*)x)[gid];
        ushort4v h, l;
        float c[4] = {v.x, v.y, v.z, v.w};
        #pragma unroll
        for (int i = 0; i < 4; ++i) {
            unsigned short hi = f2b(c[i]);
            h[i] = hi;
            l[i] = f2b(c[i] - b2f(hi));
        }
        ((ushort4v*)xh)[gid] = h;
        ((ushort4v*)xl)[gid] = l;
    } else if (b < 1024) {               // ---- W transpose 32x32 tiles, hi/lo
        __shared__ float tile[32][33];
        const int wb = b - 768;
        const int mat = wb >> 6, tidx = wb & 63;
        const int tk = (tidx >> 3) * 32, tn = (tidx & 7) * 32;
        const float* W = (mat == 0) ? Wq : (mat == 1) ? Wk : (mat == 2) ? Wv : Wo;
        const int kk = t >> 5, nn = t & 31;
        #pragma unroll
        for (int p = 0; p < 4; ++p)
            tile[nn][kk + p * 8] = W[(size_t)(tk + kk + p * 8) * DIM + tn + nn];
        __syncthreads();
        const int n = t >> 3, kq = (t & 7) * 4;
        ushort4v h, l;
        #pragma unroll
        for (int i = 0; i < 4; ++i) {
            float v = tile[n][kq + i];
            unsigned short hi = f2b(v);
            h[i] = hi;
            l[i] = f2b(v - b2f(hi));
        }
        size_t o = (size_t)mat * DIM * DIM + (size_t)(tn + n) * DIM + tk + kq;
        *(ushort4v*)(Wth + o) = h;
        *(ushort4v*)(Wtl + o) = l;
    } else if (b < 1056) {               // ---- VT pad zero + graph ranges
        const int i = (b - 1024) * 256 + t;          // [0, 8192)
        VT[(size_t)(i >> 5) * NPAD + N_NODES + (i & 31)] = 0;
        if (i < N_NODES) {
            int bb = batch[i];
            int bp = (i == 0) ? -1 : batch[i - 1];
            for (int g = bp + 1; g <= bb; ++g) gstart[g] = i;
            if (i == N_NODES - 1)
                for (int g = bb + 1; g <= B_GRAPHS; ++g) gstart[g] = N_NODES;
        }
    } else {                             // ---- per-row edge bucket + per-edge bias
        const int e = (b - 1056) * 256 + t;
        const int row = erow[e];
        const int col = ecolin[e];
        int pos = atomicAdd(&tcur[row], 1);
        if (pos < RCAP)
            tbuck[(size_t)row * RCAP + pos] = ((unsigned int)e << 12) | (unsigned int)col;
        float4 a = ((const float4*)ea)[e];
        #pragma unroll
        for (int h = 0; h < NH; ++h) {
            float bb = fmaf(a.x, We[0 * NH + h],
                       fmaf(a.y, We[1 * NH + h],
                       fmaf(a.z, We[2 * NH + h],
                       fmaf(a.w, We[3 * NH + h], be[h]))));
            ebias[(size_t)h * E_EDGES + e] = bb;
        }
    }
}

// ---------------- K2: QKV split-bf16 MFMA ----------------
// grid 576, block 256 = 4 waves; wave tile 16x64. u: bx=u%96 (32-row block),
// by=u/96 in [0,6): mat=by>>1. mat<2 -> Q/K row-major; mat==2 -> V^T.
__global__ __launch_bounds__(256) void qkv_mfma(
    const unsigned short* __restrict__ xh, const unsigned short* __restrict__ xl,
    const unsigned short* __restrict__ Wth, const unsigned short* __restrict__ Wtl,
    const float* __restrict__ bq, const float* __restrict__ bk, const float* __restrict__ bv,
    unsigned short* __restrict__ Qb, unsigned short* __restrict__ Kb,
    unsigned short* __restrict__ VT)
{
    const int u = blockIdx.x;
    const int t = threadIdx.x;
    const int w = t >> 6, lane = t & 63;
    const int l16 = lane & 15, lq = lane >> 4;
    const int bx = u % 96, by = u / 96;
    const int mat = by >> 1;
    const int rb = bx * 32 + (w & 1) * 16;
    const int nb = (by & 1) * 128 + (w >> 1) * 64;
    const unsigned short* Wh = Wth + (size_t)mat * DIM * DIM;
    const unsigned short* Wl = Wtl + (size_t)mat * DIM * DIM;

    f32x4 acc[4] = {{0,0,0,0},{0,0,0,0},{0,0,0,0},{0,0,0,0}};

    if (mat < 2) {                       // ---- Q/K: A = x rows, B = W^T rows
        const size_t arow = (size_t)(rb + l16) * DIM + (lq << 3);
        #pragma unroll
        for (int kc = 0; kc < 8; ++kc) {
            const int k = kc * 32;
            bf16x8 ah = *(const bf16x8*)(xh + arow + k);
            bf16x8 al = *(const bf16x8*)(xl + arow + k);
            #pragma unroll
            for (int ct = 0; ct < 4; ++ct) {
                const size_t bo_ = (size_t)(nb + ct * 16 + l16) * DIM + k + (lq << 3);
                bf16x8 bh = *(const bf16x8*)(Wh + bo_);
                bf16x8 bl = *(const bf16x8*)(Wl + bo_);
                acc[ct] = __builtin_amdgcn_mfma_f32_16x16x32_bf16(ah, bh, acc[ct], 0, 0, 0);
                acc[ct] = __builtin_amdgcn_mfma_f32_16x16x32_bf16(ah, bl, acc[ct], 0, 0, 0);
                acc[ct] = __builtin_amdgcn_mfma_f32_16x16x32_bf16(al, bh, acc[ct], 0, 0, 0);
            }
        }
        const float* bias = (mat == 0) ? bq : bk;
        unsigned short* outp = (mat == 0) ? Qb : Kb;
        #pragma unroll
        for (int ct = 0; ct < 4; ++ct) {
            const int n = nb + ct * 16 + l16;
            const float bvl = bias[n];
            #pragma unroll
            for (int r = 0; r < 4; ++r)
                outp[(size_t)(rb + lq * 4 + r) * DIM + n] = f2b(acc[ct][r] + bvl);
        }
    } else {                             // ---- V^T: A = Wv^T rows, B = x rows
        const size_t brow = (size_t)(rb + l16) * DIM + (lq << 3);
        #pragma unroll
        for (int kc = 0; kc < 8; ++kc) {
            const int k = kc * 32;
            bf16x8 bxh = *(const bf16x8*)(xh + brow + k);
            bf16x8 bxl = *(const bf16x8*)(xl + brow + k);
            #pragma unroll
            for (int ct = 0; ct < 4; ++ct) {
                const size_t ao_ = (size_t)(nb + ct * 16 + l16) * DIM + k + (lq << 3);
                bf16x8 awh = *(const bf16x8*)(Wh + ao_);
                bf16x8 awl = *(const bf16x8*)(Wl + ao_);
                acc[ct] = __builtin_amdgcn_mfma_f32_16x16x32_bf16(awh, bxh, acc[ct], 0, 0, 0);
                acc[ct] = __builtin_amdgcn_mfma_f32_16x16x32_bf16(awh, bxl, acc[ct], 0, 0, 0);
                acc[ct] = __builtin_amdgcn_mfma_f32_16x16x32_bf16(awl, bxh, acc[ct], 0, 0, 0);
            }
        }
        #pragma unroll
        for (int ct = 0; ct < 4; ++ct) {
            #pragma unroll
            for (int r = 0; r < 4; ++r) {
                const int ncol = nb + ct * 16 + lq * 4 + r;   // output channel (h*HD+kout)
                VT[(size_t)ncol * NPAD + rb + l16] = f2b(acc[ct][r] + bv[ncol]);
            }
        }
    }
}

// ---------------- K3: MFMA block-diagonal attention ----------------
// grid (16 graphs, 24 tiles, 8 heads), block 256 (4 waves), TR=16 rows/tile.
// 16-aligned column base ags = gs & ~15; dead prefix cols masked P=0.
// Bias phase: row r of the tile scans exactly bucket row0+r (16 lanes/row).
__global__ __launch_bounds__(256) void attn(
    const unsigned short* __restrict__ Qb, const unsigned short* __restrict__ Kb,
    const unsigned short* __restrict__ VT,
    const int* __restrict__ gstart,
    const int* __restrict__ tcur, const unsigned int* __restrict__ tbuck,
    const float* __restrict__ ebias,
    unsigned short* __restrict__ preh, unsigned short* __restrict__ prel)
{
    __shared__ float s[TR][MAXC];                 // scores fp32; reused as PV reduce buf
    __shared__ unsigned short pb[TR][PADP];       // probabilities bf16 (A-frag layout)
    __shared__ float rowinv[TR];

    const int g = blockIdx.x, tile = blockIdx.y, h = blockIdx.z;
    const int gs = gstart[g], ge = gstart[g + 1];
    const int row0 = gs + tile * TR;
    if (row0 >= ge) return;
    const int nrows = min(TR, ge - row0);
    const int ncols = ge - gs;
    const int ags   = gs & ~15;                   // aligned column base
    const int coff  = gs - ags;                   // 0..15 dead prefix cols
    const int tcols = coff + ncols;
    const int cpad  = (tcols + 31) & ~31;
    const int t = threadIdx.x;
    const int wave = t >> 6, lane = t & 63;
    const int l16 = lane & 15, lq = lane >> 4;

    // ---- QK^T via MFMA: A = Q rows, B = K rows (head-dim contraction)
    {
        int arow = min(row0 + l16, N_NODES - 1);
        const bf16x8 aq = *(const bf16x8*)(Qb + (size_t)arow * DIM + h * HD + (lq << 3));
        const int nchunk16 = (tcols + 15) >> 4;
        for (int j = wave; j < nchunk16; j += 4) {
            const int c0 = j << 4;
            int krow = min(ags + c0 + l16, N_NODES - 1);
            bf16x8 bk = *(const bf16x8*)(Kb + (size_t)krow * DIM + h * HD + (lq << 3));
            f32x4 d = {0.f, 0.f, 0.f, 0.f};
            d = __builtin_amdgcn_mfma_f32_16x16x32_bf16(aq, bk, d, 0, 0, 0);
            const int col = c0 + l16, rbase = lq * 4;
            #pragma unroll
            for (int r = 0; r < 4; ++r) s[rbase + r][col] = d[r] * SCALE;
        }
    }
    __syncthreads();

    // ---- edge-bias scatter: per-row bucket scan (duplicates via LDS atomics)
    {
        const int r = t >> 4, sub = t & 15;
        if (r < nrows) {
            const int cnt = min(tcur[row0 + r], RCAP);
            const unsigned int* bk = tbuck + (size_t)(row0 + r) * RCAP;
            for (int idx = sub; idx < cnt; idx += 16) {
                unsigned int p = bk[idx];
                int c = (int)(p & 0xFFFu) - gs;
                if (c >= 0 && c < ncols)
                    atomicAdd(&s[r][coff + c], ebias[(size_t)h * E_EDGES + (p >> 12)]);
            }
        }
    }
    __syncthreads();

    // ---- softmax: 16 lanes/row; emit bf16 P, zero outside [coff, tcols)
    {
        const int r = t >> 4, sub = t & 15;
        if (r < nrows) {
            float m = -INFINITY;
            for (int c = coff + sub; c < tcols; c += 16) m = fmaxf(m, s[r][c]);
            m = fmaxf(m, __shfl_xor(m, 1, 16));
            m = fmaxf(m, __shfl_xor(m, 2, 16));
            m = fmaxf(m, __shfl_xor(m, 4, 16));
            m = fmaxf(m, __shfl_xor(m, 8, 16));
            float sum = 0.f;
            for (int c = sub; c < cpad; c += 16) {
                if (c >= coff && c < tcols) {
                    float e = __expf(s[r][c] - m);
                    sum += e;
                    pb[r][c] = f2b(e);
                } else {
                    pb[r][c] = 0;
                }
            }
            sum += __shfl_xor(sum, 1, 16);
            sum += __shfl_xor(sum, 2, 16);
            sum += __shfl_xor(sum, 4, 16);
            sum += __shfl_xor(sum, 8, 16);
            if (sub == 0) rowinv[r] = 1.0f / sum;
        } else {
            for (int c = sub; c < cpad; c += 16) pb[r][c] = 0;
        }
    }
    __syncthreads();

    // ---- PV via MFMA: B-frag = one aligned 16B V^T load per chunk
    f32x4 o = {0.f, 0.f, 0.f, 0.f};
    {
        const int half = wave >> 1, par = wave & 1;
        const int kout = l16 + (half << 4);
        const int nchunk32 = cpad >> 5;
        const unsigned short* vrow = VT + (size_t)(h * HD + kout) * NPAD + ags + (lq << 3);
        for (int j = par; j < nchunk32; j += 2) {
            const int c0 = j << 5;
            bf16x8 ap = *(const bf16x8*)(&pb[l16][c0 + (lq << 3)]);
            bf16x8 bv = *(const bf16x8*)(vrow + c0);
            o = __builtin_amdgcn_mfma_f32_16x16x32_bf16(ap, bv, o, 0, 0, 0);
        }
    }
    __syncthreads();
    {
        float* red = &s[0][0];       // [4 waves][16 rows][16 kout], stride 17
        const int rbase = lq * 4;
        #pragma unroll
        for (int r = 0; r < 4; ++r)
            red[((wave << 4) + rbase + r) * 17 + l16] = o[r];
    }
    __syncthreads();
    {
        const int row = t >> 4, kl = t & 15;
        if (row < nrows) {
            float* red = &s[0][0];
            float v0 = red[(row) * 17 + kl]        + red[(16 + row) * 17 + kl];
            float v1 = red[(32 + row) * 17 + kl]   + red[(48 + row) * 17 + kl];
            float sc = rowinv[row];
            size_t ob = (size_t)(row0 + row) * DIM + h * HD;
            float f0 = v0 * sc, f1 = v1 * sc;
            unsigned short h0 = f2b(f0), h1 = f2b(f1);
            preh[ob + kl]      = h0;
            preh[ob + 16 + kl] = h1;
            prel[ob + kl]      = f2b(f0 - b2f(h0));
            prel[ob + 16 + kl] = f2b(f1 - b2f(h1));
        }
    }
}

// ---------------- K4: output projection via split-bf16 MFMA ----------------
__global__ __launch_bounds__(256) void out_mfma(
    const unsigned short* __restrict__ preh, const unsigned short* __restrict__ prel,
    const unsigned short* __restrict__ Wth, const unsigned short* __restrict__ Wtl,
    const float* __restrict__ bo, float* __restrict__ out)
{
    const int t = threadIdx.x, w = t >> 6, lane = t & 63;
    const int l16 = lane & 15, lq = lane >> 4;
    const int rb = blockIdx.x * 16;
    const int nb = blockIdx.y * 128 + w * 32;
    const unsigned short* Wh = Wth + (size_t)3 * DIM * DIM;   // Wo^T
    const unsigned short* Wl = Wtl + (size_t)3 * DIM * DIM;

    f32x4 acc[2] = {{0,0,0,0},{0,0,0,0}};
    const size_t arow = (size_t)(rb + l16) * DIM + (lq << 3);

    #pragma unroll
    for (int kc = 0; kc < 8; ++kc) {
        const int k = kc * 32;
        bf16x8 ah = *(const bf16x8*)(preh + arow + k);
        bf16x8 al = *(const bf16x8*)(prel + arow + k);
        #pragma unroll
        for (int ct = 0; ct < 2; ++ct) {
            const size_t bo_ = (size_t)(nb + ct * 16 + l16) * DIM + k + (lq << 3);
            bf16x8 bh = *(const bf16x8*)(Wh + bo_);
            bf16x8 bl = *(const bf16x8*)(Wl + bo_);
            acc[ct] = __builtin_amdgcn_mfma_f32_16x16x32_bf16(ah, bh, acc[ct], 0, 0, 0);
            acc[ct] = __builtin_amdgcn_mfma_f32_16x16x32_bf16(ah, bl, acc[ct], 0, 0, 0);
            acc[ct] = __builtin_amdgcn_mfma_f32_16x16x32_bf16(al, bh, acc[ct], 0, 0, 0);
        }
    }

    #pragma unroll
    for (int ct = 0; ct < 2; ++ct) {
        const int n = nb + ct * 16 + l16;
        const float bvl = bo[n];
        #pragma unroll
        for (int r = 0; r < 4; ++r)
            out[(size_t)(rb + lq * 4 + r) * DIM + n] = acc[ct][r] + bvl;
    }
}

// ---------------- launch ----------------
extern "C" void kernel_launch(void* const* d_in, const int* in_sizes, int n_in,
                              void* d_out, int out_size, void* d_ws, size_t ws_size,
                              hipStream_t stream) {
    const float* x   = (const float*)d_in[0];
    const float* ea  = (const float*)d_in[1];
    const float* Wq  = (const float*)d_in[2];  const float* bq = (const float*)d_in[3];
    const float* Wk  = (const float*)d_in[4];  const float* bk = (const float*)d_in[5];
    const float* Wv  = (const float*)d_in[6];  const float* bv = (const float*)d_in[7];
    const float* Wo  = (const float*)d_in[8];  const float* bo = (const float*)d_in[9];
    const float* We  = (const float*)d_in[10]; const float* be = (const float*)d_in[11];
    const int*   eidx  = (const int*)d_in[12];
    const int*   batch = (const int*)d_in[13];
    const int* erow   = eidx;
    const int* ecolin = eidx + E_EDGES;

    const size_t ND = (size_t)N_NODES * DIM;     // 786432
    const size_t WD = (size_t)DIM * DIM;         // 65536

    unsigned short* Qb   = (unsigned short*)d_ws;
    unsigned short* Kb   = Qb + ND;
    unsigned short* VT   = Kb + ND;              // [256][NPAD]
    unsigned short* preh = VT + (size_t)DIM * NPAD;
    unsigned short* prel = preh + ND;
    unsigned short* xh   = prel + ND;
    unsigned short* xl   = xh + ND;
    unsigned short* Wth  = xl + ND;              // 4 * WD
    unsigned short* Wtl  = Wth + 4 * WD;
    unsigned int* tbuck  = (unsigned int*)(Wtl + 4 * WD);       // N_NODES * RCAP u32
    float* ebias  = (float*)(tbuck + (size_t)N_NODES * RCAP);   // [NH][E]
    int* tcur     = (int*)(ebias + (size_t)NH * E_EDGES);       // N_NODES
    int* gstart   = tcur + N_NODES;                             // B+1

    hipMemsetAsync(tcur, 0, N_NODES * sizeof(int), stream);
    prep<<<dim3(1440), dim3(256), 0, stream>>>(x, Wq, Wk, Wv, Wo, ea, We, be,
                                               erow, ecolin, xh, xl, Wth, Wtl,
                                               VT, ebias, batch, gstart, tcur, tbuck);
    qkv_mfma<<<dim3(576), dim3(256), 0, stream>>>(xh, xl, Wth, Wtl, bq, bk, bv,
                                                  Qb, Kb, VT);
    attn<<<dim3(B_GRAPHS, 24, NH), dim3(256), 0, stream>>>(Qb, Kb, VT, gstart,
                                                           tcur, tbuck, ebias, preh, prel);
    out_mfma<<<dim3(192, 2), dim3(256), 0, stream>>>(preh, prel, Wth, Wtl, bo, (float*)d_out);
}